// Round 2
// baseline (639.242 us; speedup 1.0000x reference)
//
#include <hip/hip_runtime.h>

typedef __bf16 bf16x8 __attribute__((ext_vector_type(8)));
typedef float  f32x4  __attribute__((ext_vector_type(4)));

#define NTOK  49
#define CDIM  128
#define QK_SCALE 0.17677669529663687f   // 1/sqrt(32)

// LDS strides (elements).
#define XS 136   // lds_x  [64][136]  (x bf16, later O bf16)
#define QS 264   // lds_qkv[64][264]  (cols 0..127 = q*scale, 128..255 = k)
#define VS 72    // lds_vt [128][72]  (v transposed: [h*32+d][row])
#define PS 64    // lds_p  [4][64][64] aliases lds_qkv. MUST be >=64: cols j=0..63
                 // are written (j>=49 are ~0 but still stored) and phase 3 reads
                 // k-slices up to j=63. PS=56 was the round-1 correctness bug.

// workspace offsets (bytes)
#define WQKV_OFF  0          // 384*128 bf16 = 98304 B
#define WPROJ_OFF 98304      // 128*128 bf16 = 32768 B
#define BIASF_OFF 131072     // 4*49*49 f32  = 38416 B

__global__ void prep_kernel(const float* __restrict__ qkv_w,
                            const float* __restrict__ proj_w,
                            const float* __restrict__ bias_table,
                            const int*   __restrict__ rel_index,
                            __bf16* __restrict__ wqkv,
                            __bf16* __restrict__ wproj,
                            float*  __restrict__ biasf) {
    int t = blockIdx.x * 256 + threadIdx.x;
    if (t < 384 * 128) wqkv[t]  = (__bf16)qkv_w[t];
    if (t < 128 * 128) wproj[t] = (__bf16)proj_w[t];
    if (t < 4 * 2401) {
        int h = t / 2401, ij = t % 2401;
        biasf[t] = bias_table[rel_index[ij] * 4 + h];   // bias_full[h][i][j]
    }
}

__launch_bounds__(256, 2)
__global__ void winattn_kernel(const float* __restrict__ x,
                               const float* __restrict__ mask,
                               const float* __restrict__ qkv_b,
                               const float* __restrict__ proj_b,
                               const __bf16* __restrict__ wqkv,
                               const __bf16* __restrict__ wproj,
                               const float* __restrict__ biasf,
                               float* __restrict__ out) {
    __shared__ __bf16 lds_x[64 * XS];
    __shared__ __bf16 lds_qkv[64 * QS];
    __shared__ __bf16 lds_vt[128 * VS];
    __bf16* lds_p = lds_qkv;   // alias: q/k dead before p is written (barriered)

    const int tid  = threadIdx.x;
    const int w    = blockIdx.x;
    const int wave = tid >> 6;
    const int lane = tid & 63;
    const int quad = lane >> 4;
    const int l16  = lane & 15;

    // ---------------- phase 0: x (fp32) -> lds_x (bf16), rows>=49 zeroed ----
    {
        int row = tid >> 2;           // 0..63
        int c0  = (tid & 3) * 32;     // 0,32,64,96
        __align__(16) __bf16 tmp[32];
        if (row < NTOK) {
            const float4* src = (const float4*)(x + ((size_t)w * NTOK + row) * CDIM + c0);
            #pragma unroll
            for (int i = 0; i < 8; ++i) {
                float4 f = src[i];
                tmp[i*4+0] = (__bf16)f.x; tmp[i*4+1] = (__bf16)f.y;
                tmp[i*4+2] = (__bf16)f.z; tmp[i*4+3] = (__bf16)f.w;
            }
        } else {
            #pragma unroll
            for (int i = 0; i < 32; ++i) tmp[i] = (__bf16)0.0f;
        }
        bf16x8* dst = (bf16x8*)&lds_x[row * XS + c0];
        #pragma unroll
        for (int i = 0; i < 4; ++i) dst[i] = *(bf16x8*)&tmp[i*8];
    }
    __syncthreads();

    // ---------------- phase 1: qkv = x @ Wqkv^T + b ------------------------
    #pragma unroll
    for (int half = 0; half < 2; ++half) {
        f32x4 acc[3][4];
        #pragma unroll
        for (int a = 0; a < 3; ++a)
            #pragma unroll
            for (int b = 0; b < 4; ++b) acc[a][b] = (f32x4){0.f,0.f,0.f,0.f};

        #pragma unroll
        for (int kt = 0; kt < 4; ++kt) {
            bf16x8 a4[4];
            #pragma unroll
            for (int mt = 0; mt < 4; ++mt)
                a4[mt] = *(bf16x8*)&lds_x[(mt*16 + l16) * XS + kt*32 + quad*8];
            #pragma unroll
            for (int ntl = 0; ntl < 3; ++ntl) {
                int o = (wave*6 + half*3 + ntl) * 16 + l16;    // 0..383
                bf16x8 bf = *(const bf16x8*)(wqkv + (size_t)o * CDIM + kt*32 + quad*8);
                #pragma unroll
                for (int mt = 0; mt < 4; ++mt)
                    acc[ntl][mt] = __builtin_amdgcn_mfma_f32_16x16x32_bf16(
                        a4[mt], bf, acc[ntl][mt], 0, 0, 0);
            }
        }
        #pragma unroll
        for (int ntl = 0; ntl < 3; ++ntl) {
            int o = (wave*6 + half*3 + ntl) * 16 + l16;
            float b = qkv_b[o];
            #pragma unroll
            for (int mt = 0; mt < 4; ++mt) {
                #pragma unroll
                for (int r = 0; r < 4; ++r) {
                    int row = mt*16 + quad*4 + r;
                    float v = acc[ntl][mt][r] + b;
                    if (o < 128)       lds_qkv[row * QS + o] = (__bf16)(v * QK_SCALE);
                    else if (o < 256)  lds_qkv[row * QS + o] = (__bf16)v;
                    else               lds_vt[(o - 256) * VS + row] = (__bf16)v; // [h*32+d][row]
                }
            }
        }
    }
    __syncthreads();

    // ---------------- phase 2: S = q k^T + bias + mask; softmax ------------
    {
        const int h = wave;
        bf16x8 bk[4];
        #pragma unroll
        for (int nt = 0; nt < 4; ++nt)
            bk[nt] = *(bf16x8*)&lds_qkv[(nt*16 + l16) * QS + 128 + h*32 + quad*8];

        f32x4 s[4][4];
        #pragma unroll
        for (int mt = 0; mt < 4; ++mt) {
            bf16x8 aq = *(bf16x8*)&lds_qkv[(mt*16 + l16) * QS + h*32 + quad*8];
            #pragma unroll
            for (int nt = 0; nt < 4; ++nt) {
                f32x4 z = (f32x4){0.f,0.f,0.f,0.f};
                s[mt][nt] = __builtin_amdgcn_mfma_f32_16x16x32_bf16(aq, bk[nt], z, 0, 0, 0);
            }
        }

        const float* bh = biasf + h * 2401;
        const float* mh = mask + (size_t)(w & 63) * 2401;
        #pragma unroll
        for (int mt = 0; mt < 4; ++mt) {
            #pragma unroll
            for (int r = 0; r < 4; ++r) {
                int i = mt*16 + quad*4 + r;
                float v[4];
                #pragma unroll
                for (int nt = 0; nt < 4; ++nt) {
                    int j = nt*16 + l16;
                    float t = s[mt][nt][r];
                    if (j < NTOK) { if (i < NTOK) t += bh[i*49 + j] + mh[i*49 + j]; }
                    else t = -1e30f;
                    v[nt] = t;
                }
                float mx = fmaxf(fmaxf(v[0], v[1]), fmaxf(v[2], v[3]));
                mx = fmaxf(mx, __shfl_xor(mx, 1, 64));
                mx = fmaxf(mx, __shfl_xor(mx, 2, 64));
                mx = fmaxf(mx, __shfl_xor(mx, 4, 64));
                mx = fmaxf(mx, __shfl_xor(mx, 8, 64));
                float e[4], sum = 0.f;
                #pragma unroll
                for (int nt = 0; nt < 4; ++nt) { e[nt] = __expf(v[nt] - mx); sum += e[nt]; }
                sum += __shfl_xor(sum, 1, 64);
                sum += __shfl_xor(sum, 2, 64);
                sum += __shfl_xor(sum, 4, 64);
                sum += __shfl_xor(sum, 8, 64);
                float inv = 1.0f / sum;
                #pragma unroll
                for (int nt = 0; nt < 4; ++nt) s[mt][nt][r] = e[nt] * inv;
            }
        }
        __syncthreads();   // all waves done READING lds_qkv before p overwrites it
        #pragma unroll
        for (int mt = 0; mt < 4; ++mt)
            #pragma unroll
            for (int r = 0; r < 4; ++r)
                #pragma unroll
                for (int nt = 0; nt < 4; ++nt)
                    lds_p[((h << 6) + mt*16 + quad*4 + r) * PS + nt*16 + l16] =
                        (__bf16)s[mt][nt][r];
    }
    __syncthreads();

    // ---------------- phase 3: O = P @ V -----------------------------------
    {
        const int h = wave;
        bf16x8 bv[2][2];
        #pragma unroll
        for (int nv = 0; nv < 2; ++nv)
            #pragma unroll
            for (int kt = 0; kt < 2; ++kt)
                bv[nv][kt] = *(bf16x8*)&lds_vt[(h*32 + nv*16 + l16) * VS + kt*32 + quad*8];

        f32x4 oacc[4][2];
        #pragma unroll
        for (int a = 0; a < 4; ++a)
            #pragma unroll
            for (int b = 0; b < 2; ++b) oacc[a][b] = (f32x4){0.f,0.f,0.f,0.f};

        #pragma unroll
        for (int mt = 0; mt < 4; ++mt)
            #pragma unroll
            for (int kt = 0; kt < 2; ++kt) {
                bf16x8 ap = *(bf16x8*)&lds_p[((h << 6) + mt*16 + l16) * PS + kt*32 + quad*8];
                #pragma unroll
                for (int nv = 0; nv < 2; ++nv)
                    oacc[mt][nv] = __builtin_amdgcn_mfma_f32_16x16x32_bf16(
                        ap, bv[nv][kt], oacc[mt][nv], 0, 0, 0);
            }

        // write O into lds_x (x is dead since phase 1)
        #pragma unroll
        for (int mt = 0; mt < 4; ++mt)
            #pragma unroll
            for (int nv = 0; nv < 2; ++nv)
                #pragma unroll
                for (int r = 0; r < 4; ++r) {
                    int row = mt*16 + quad*4 + r;
                    lds_x[row * XS + h*32 + nv*16 + l16] = (__bf16)oacc[mt][nv][r];
                }
    }
    __syncthreads();

    // ---------------- phase 4: out = O @ Wproj^T + b ------------------------
    #pragma unroll
    for (int ntl = 0; ntl < 2; ++ntl) {
        int o = (wave*2 + ntl) * 16 + l16;     // 0..127
        f32x4 acc[4];
        #pragma unroll
        for (int a = 0; a < 4; ++a) acc[a] = (f32x4){0.f,0.f,0.f,0.f};
        #pragma unroll
        for (int kt = 0; kt < 4; ++kt) {
            bf16x8 bf = *(const bf16x8*)(wproj + (size_t)o * CDIM + kt*32 + quad*8);
            #pragma unroll
            for (int mt = 0; mt < 4; ++mt) {
                bf16x8 af = *(bf16x8*)&lds_x[(mt*16 + l16) * XS + kt*32 + quad*8];
                acc[mt] = __builtin_amdgcn_mfma_f32_16x16x32_bf16(af, bf, acc[mt], 0, 0, 0);
            }
        }
        float pb = proj_b[o];
        #pragma unroll
        for (int mt = 0; mt < 4; ++mt)
            #pragma unroll
            for (int r = 0; r < 4; ++r) {
                int row = mt*16 + quad*4 + r;
                if (row < NTOK)
                    out[((size_t)w * NTOK + row) * CDIM + o] = acc[mt][r] + pb;
            }
    }
}

extern "C" void kernel_launch(void* const* d_in, const int* in_sizes, int n_in,
                              void* d_out, int out_size, void* d_ws, size_t ws_size,
                              hipStream_t stream) {
    const float* x          = (const float*)d_in[0];
    const float* mask       = (const float*)d_in[1];
    const float* qkv_w      = (const float*)d_in[2];
    const float* qkv_b      = (const float*)d_in[3];
    const float* proj_w     = (const float*)d_in[4];
    const float* proj_b     = (const float*)d_in[5];
    const float* bias_table = (const float*)d_in[6];
    const int*   rel_index  = (const int*)d_in[7];

    __bf16* wqkv  = (__bf16*)((char*)d_ws + WQKV_OFF);
    __bf16* wproj = (__bf16*)((char*)d_ws + WPROJ_OFF);
    float*  biasf = (float*)((char*)d_ws + BIASF_OFF);

    int nwb = in_sizes[0] / (NTOK * CDIM);   // 8192

    prep_kernel<<<192, 256, 0, stream>>>(qkv_w, proj_w, bias_table, rel_index,
                                         wqkv, wproj, biasf);
    winattn_kernel<<<nwb, 256, 0, stream>>>(x, mask, qkv_b, proj_b,
                                            wqkv, wproj, biasf, (float*)d_out);
}